// Round 14
// baseline (875.044 us; speedup 1.0000x reference)
//
#include <hip/hip_runtime.h>
#include <cstdint>
#include <cstddef>

using bf16x8 = __attribute__((ext_vector_type(8))) short;
using f32x4  = __attribute__((ext_vector_type(4))) float;

constexpr int kB = 8192;
constexpr int kD = 1024;
constexpr int kE = 8;
constexpr int kH = 4096;
constexpr int kC = 10;

__device__ __forceinline__ unsigned short f2bf(float f) {
  unsigned int u = __float_as_uint(f);
  u += 0x7FFFu + ((u >> 16) & 1u);   // round-to-nearest-even (finite inputs)
  return (unsigned short)(u >> 16);
}

#define GLD16(gptr, lptr)                                                      \
  __builtin_amdgcn_global_load_lds(                                            \
      (const __attribute__((address_space(1))) void*)(gptr),                   \
      (__attribute__((address_space(3))) void*)(lptr), 16, 0, 0)

// ============================================================================
// k_prep_all: ONE launch for the whole preamble.  Flat-grid partition over
// six independent jobs (disjoint outputs; branch is uniform per block).
// vbuild reads Wc directly from cache (no 40KB LDS -> no r6-style occupancy
// collapse); static LDS = 2.1 KB transpose tile only.
//   [0, 32768)      transpose W1 [E][D][H] f32 -> W1t [E][H][D] bf16
//   [32768, 33280)  vbuild: Vt[e][c][h] = sum_d W2[e][h][d]*Wc[d][c]
//   [33280, 37376)  convert x -> bf16
//   [37376, 39424)  routing softmax
//   [39424, 39936)  zero part
//   [39936]         ubuild
// ============================================================================
__global__ __launch_bounds__(256) void k_prep_all(
    const float* __restrict__ x,  const float* __restrict__ Wr,
    const float* __restrict__ br, const float* __restrict__ W1,
    const float* __restrict__ W2, const float* __restrict__ Wc,
    const float* __restrict__ b2,
    unsigned short* __restrict__ xb, unsigned short* __restrict__ W1t,
    unsigned short* __restrict__ Vt,
    float* __restrict__ r, float* __restrict__ part, float* __restrict__ u) {
  __shared__ unsigned short tile[32][33];
  const int bid = blockIdx.x;
  const int t = threadIdx.x;
  if (bid < 32768) {  // ---- transpose W1 (per-e 128 n-tiles x 32 k-tiles) ----
    const int e = bid >> 12, rem = bid & 4095;
    const int n0 = (rem & 127) * 32, k0 = (rem >> 7) * 32;
    const int tx = t & 31, ty = t >> 5;
    const float* Wb = W1 + (size_t)e * kD * kH;
    unsigned short* Wtb = W1t + (size_t)e * kH * kD;
#pragma unroll
    for (int j = 0; j < 32; j += 8)
      tile[ty + j][tx] = f2bf(Wb[(size_t)(k0 + ty + j) * kH + n0 + tx]);
    __syncthreads();
#pragma unroll
    for (int j = 0; j < 32; j += 8)
      Wtb[(size_t)(n0 + ty + j) * kD + k0 + tx] = tile[tx][ty + j];
  } else if (bid < 33280) {  // ---- vbuild: 4 lanes per row, Wc via cache ----
    const int gid = (bid - 32768) * 256 + t;  // 0..131071
    const int row = gid >> 2, q = gid & 3;
    const int e = row >> 12, hrow = row & 4095;
    const float4* w2q = reinterpret_cast<const float4*>(W2 + (size_t)row * kD + q * 256);
    float acc[kC];
#pragma unroll
    for (int c = 0; c < kC; ++c) acc[c] = 0.f;
#pragma unroll 4
    for (int i = 0; i < 64; ++i) {
      float4 w = w2q[i];
      const float* wc0 = Wc + (q * 256 + i * 4) * kC;
#pragma unroll
      for (int c = 0; c < kC; ++c)
        acc[c] += w.x * wc0[c] + w.y * wc0[kC + c] + w.z * wc0[2 * kC + c] +
                  w.w * wc0[3 * kC + c];
    }
#pragma unroll
    for (int c = 0; c < kC; ++c) {
      acc[c] += __shfl_xor(acc[c], 1);
      acc[c] += __shfl_xor(acc[c], 2);
    }
    if (q == 0) {
      unsigned short* vte = Vt + (size_t)e * 16 * kH;
#pragma unroll
      for (int c = 0; c < kC; ++c) vte[(size_t)c * kH + hrow] = f2bf(acc[c]);
#pragma unroll
      for (int c = kC; c < 16; ++c) vte[(size_t)c * kH + hrow] = 0;
    }
  } else if (bid < 37376) {  // ---- convert x ----
    const long i = ((long)(bid - 33280) * 256 + t) * 8;
    float4 a = *reinterpret_cast<const float4*>(x + i);
    float4 b = *reinterpret_cast<const float4*>(x + i + 4);
    bf16x8 o;
    o[0] = (short)f2bf(a.x); o[1] = (short)f2bf(a.y);
    o[2] = (short)f2bf(a.z); o[3] = (short)f2bf(a.w);
    o[4] = (short)f2bf(b.x); o[5] = (short)f2bf(b.y);
    o[6] = (short)f2bf(b.z); o[7] = (short)f2bf(b.w);
    *reinterpret_cast<bf16x8*>(xb + i) = o;
  } else if (bid < 39424) {  // ---- routing softmax ----
    const int w = t >> 6, l = t & 63;
    const int b = (bid - 37376) * 4 + w;
    const float* xr = x + (size_t)b * kD;
    float acc[kE];
#pragma unroll
    for (int e = 0; e < kE; ++e) acc[e] = 0.f;
    for (int d = l; d < kD; d += 64) {
      const float xv = xr[d];
      const float* wrow = Wr + d * kE;
#pragma unroll
      for (int e = 0; e < kE; ++e) acc[e] += xv * wrow[e];
    }
#pragma unroll
    for (int e = 0; e < kE; ++e) {
#pragma unroll
      for (int s = 32; s > 0; s >>= 1) acc[e] += __shfl_xor(acc[e], s);
      acc[e] += br[e];
    }
    float mx = acc[0];
#pragma unroll
    for (int e = 1; e < kE; ++e) mx = fmaxf(mx, acc[e]);
    float sum = 0.f;
#pragma unroll
    for (int e = 0; e < kE; ++e) { acc[e] = expf(acc[e] - mx); sum += acc[e]; }
    const float inv = 1.f / sum;
    float val = 0.f;
#pragma unroll
    for (int e = 0; e < kE; ++e) if (l == e) val = acc[e] * inv;
    if (l < kE) r[(size_t)b * kE + l] = val;
  } else if (bid < 39936) {  // ---- zero part ----
    part[(size_t)(bid - 39424) * 256 + t] = 0.f;
  } else {  // ---- ubuild ----
    if (t >= kE * kC) return;
    const int e = t / kC, c = t % kC;
    float acc = 0.f;
    for (int d = 0; d < kD; ++d) acc += b2[e * kD + d] * Wc[d * kC + c];
    u[e * 16 + c] = acc;
  }
}

// ============================================================================
// fused 256x256 8-phase GEMM1 + V-contraction  (r10 + one tweak)
//   part[b][c] += r[b,e] * sum_h relu(x@W1[e]+b1[e])[b,h] * Vt[e][c][h]
// TWEAK vs r10: ph1 stages BOTH Y.A halves (ph2's STG_A moved to ph1) ->
// Y.A gets one extra phase of DMA flight before the ph4 gate.  Ledger
// unchanged: ph4 outstanding = Y.B(4,oldest)+Y.A(4)+X'.B(4,newest)=12,
// vmcnt(4) drains exactly KT(2i+1); ph8 = X'.B+X'.A+Y'.B=12, vmcnt(4)
// drains KT(2i+2).  WAR: both Y.A halves free since prev ph8's barrier.
// HARD WALLS (measured r5/r7/r8/r11/r12): no reg-prefetch (VGPR spill), no
// >128KB LDS, no B-from-global (latency), no in-block e-loop (L2 locality).
// ============================================================================
__global__ __launch_bounds__(512, 2) void k_moe_fused256(
    const unsigned short* __restrict__ xb,   // [B][D] bf16
    const unsigned short* __restrict__ W1t,  // [E][H][D] bf16
    const float* __restrict__ b1,            // [E][H]
    const unsigned short* __restrict__ Vt,   // [E][16][H] bf16
    const float* __restrict__ rr,            // [B][E]
    float* __restrict__ part) {              // [B][16] f32 (atomic accum)
  __shared__ __align__(16) char smem[131072];
  constexpr int K = kD;          // 1024
  constexpr int NIT = K / 128;   // 8 iterations, 2 K-tiles (BK=64) each

  const int e = blockIdx.z;
  const int bx = (blockIdx.x & 7) * 4 + (blockIdx.x >> 3);  // bijective XCD swizzle (32%8==0)
  const int brow = bx * 256, bcol = blockIdx.y * 256;
  const unsigned short* const At = xb;
  const unsigned short* const Bt = W1t + (size_t)e * kH * kD;

  const int tid = threadIdx.x;
  const int w = tid >> 6, l = tid & 63;
  const int wr = w >> 2, wc = w & 3;       // wave grid 2M x 4N
  const int fr = l & 15, jg = l >> 4;      // fragment row / k-chunk group

  // fragment-read swizzled chunk offsets (row&7 == fr&7 since all row bases %16==0)
  int ck[2];
#pragma unroll
  for (int k = 0; k < 2; ++k) ck[k] = (((k * 4 + jg) ^ (fr & 7)) << 4);
  const int abase = wr * 16384;                 // + buf*65536           (A region)
  const int bbase = 32768 + (wc >> 1) * 16384;  // + buf*65536           (B region)
  const int brow0 = (wc & 1) * 64;              // B row base within half

  // staging: linear LDS dest, inverse-swizzled global source (rule 21)
  const int p0 = w * 64 + l;            // phys 16B chunk within an 8KB round
  const int rp = p0 >> 3;               // row 0..63 (round 0); +64 for round 1
  const int cs = (p0 & 7) ^ (rp & 7);   // logical chunk (same both rounds)
  const size_t aofs = (size_t)(brow + rp) * K + cs * 8;
  const size_t bofs = (size_t)(bcol + rp) * K + cs * 8;
  const int ldst = w * 1024;            // wave-uniform LDS dest offset

#define STG_A(buf, ht, kt)                                                     \
  do {                                                                         \
    GLD16(At + aofs + (size_t)(ht) * 131072 + (size_t)(kt) * 64,               \
          smem + (buf) * 65536 + (ht) * 16384 + ldst);                         \
    GLD16(At + aofs + (size_t)(ht) * 131072 + 65536 + (size_t)(kt) * 64,       \
          smem + (buf) * 65536 + (ht) * 16384 + 8192 + ldst);                  \
  } while (0)
#define STG_B(buf, ht, kt)                                                     \
  do {                                                                         \
    GLD16(Bt + bofs + (size_t)(ht) * 131072 + (size_t)(kt) * 64,               \
          smem + (buf) * 65536 + 32768 + (ht) * 16384 + ldst);                 \
    GLD16(Bt + bofs + (size_t)(ht) * 131072 + 65536 + (size_t)(kt) * 64,       \
          smem + (buf) * 65536 + 32768 + (ht) * 16384 + 8192 + ldst);          \
  } while (0)

#define READ_A(buf, mp)                                                        \
  do {                                                                         \
    _Pragma("unroll") for (int mm = 0; mm < 2; ++mm)                           \
    _Pragma("unroll") for (int k = 0; k < 2; ++k)                              \
      aq[mm][k] = *reinterpret_cast<const bf16x8*>(                            \
          smem + (buf) * 65536 + abase + (((mp) * 2 + mm) * 16 + fr) * 128 + ck[k]); \
  } while (0)
#define READ_B(buf)                                                            \
  do {                                                                         \
    _Pragma("unroll") for (int n = 0; n < 4; ++n)                              \
    _Pragma("unroll") for (int k = 0; k < 2; ++k)                              \
      bq[n][k] = *reinterpret_cast<const bf16x8*>(                             \
          smem + (buf) * 65536 + bbase + (brow0 + n * 16 + fr) * 128 + ck[k]); \
  } while (0)
#define MFMA16(mp)                                                             \
  do {                                                                         \
    __builtin_amdgcn_s_setprio(1);                                             \
    _Pragma("unroll") for (int mm = 0; mm < 2; ++mm)                           \
    _Pragma("unroll") for (int n = 0; n < 4; ++n)                              \
    _Pragma("unroll") for (int k = 0; k < 2; ++k)                              \
      acc[(mp) * 2 + mm][n] = __builtin_amdgcn_mfma_f32_16x16x32_bf16(         \
          aq[mm][k], bq[n][k], acc[(mp) * 2 + mm][n], 0, 0, 0);                \
    __builtin_amdgcn_s_setprio(0);                                             \
  } while (0)
#define BARP() asm volatile("s_barrier" ::: "memory")

  bf16x8 aq[2][2], bq[4][2];
  f32x4 acc[8][4];
#pragma unroll
  for (int m = 0; m < 8; ++m)
#pragma unroll
    for (int n = 0; n < 4; ++n) acc[m][n] = (f32x4){0.f, 0.f, 0.f, 0.f};

  // prologue: X=buf0 gets KT0 (full), Y=buf1 gets KT1's B halves; Y.A comes in ph1
  STG_A(0, 0, 0); STG_A(0, 1, 0); STG_B(0, 0, 0); STG_B(0, 1, 0);
  STG_B(1, 0, 1); STG_B(1, 1, 1);
  asm volatile("s_waitcnt vmcnt(4)" ::: "memory");  // KT0 landed; Y.B (4) in flight
  BARP();

  for (int i = 0; i < NIT; ++i) {
    const bool g = (i < NIT - 1);
    const int kx = 2 * i + 2, ky = 2 * i + 3;
    // ---- ph1: X m-pair0; stage BOTH Y.A halves [Y.A free since prev ph8] ----
    READ_A(0, 0); READ_B(0);
    STG_A(1, 0, 2 * i + 1); STG_A(1, 1, 2 * i + 1);
    BARP(); MFMA16(0); BARP();
    // ---- ph2: X m-pair1; stage X'.B0 [X.B free after ph1] ----
    READ_A(0, 1);
    if (g) STG_B(0, 0, kx);
    BARP(); MFMA16(1); BARP();
    // ---- ph3: X m-pair2; stage X'.B1 ----
    READ_A(0, 2);
    if (g) STG_B(0, 1, kx);
    BARP(); MFMA16(2); BARP();
    // ---- ph4: X m-pair3; vmcnt forces Y=KT(2i+1) complete ----
    READ_A(0, 3);
    BARP(); MFMA16(3);
    if (g) asm volatile("s_waitcnt vmcnt(4)" ::: "memory");
    else   asm volatile("s_waitcnt vmcnt(0)" ::: "memory");
    BARP();
    // ---- ph5: Y m-pair0; stage X'.A0+A1 [X.A free after ph4] ----
    READ_A(1, 0); READ_B(1);
    if (g) { STG_A(0, 0, kx); STG_A(0, 1, kx); }
    BARP(); MFMA16(0); BARP();
    // ---- ph6: Y m-pair1; stage Y'.B0 [Y.B free after ph5] ----
    READ_A(1, 1);
    if (g) STG_B(1, 0, ky);
    BARP(); MFMA16(1); BARP();
    // ---- ph7: Y m-pair2; stage Y'.B1 ----
    READ_A(1, 2);
    if (g) STG_B(1, 1, ky);
    BARP(); MFMA16(2); BARP();
    // ---- ph8: Y m-pair3; vmcnt forces X'=KT(2i+2) complete ----
    READ_A(1, 3);
    BARP(); MFMA16(3);
    if (g) asm volatile("s_waitcnt vmcnt(4)" ::: "memory");
    BARP();
  }
#undef STG_A
#undef STG_B
#undef READ_A
#undef READ_B

  // ===== epilogue: g = relu(acc+b1) -> LDS [256][256] bf16 (swizzled), then g x V^T =====
#pragma unroll
  for (int n = 0; n < 4; ++n) {
    const int lcol = wc * 64 + n * 16 + fr;
    const float bias = b1[(size_t)e * kH + bcol + lcol];
    const int cbyte = (lcol >> 3) << 4;
#pragma unroll
    for (int m = 0; m < 8; ++m) {
#pragma unroll
      for (int j = 0; j < 4; ++j) {
        const int lrow = wr * 128 + m * 16 + jg * 4 + j;
        const float v = fmaxf(acc[m][n][j] + bias, 0.f);
        *reinterpret_cast<unsigned short*>(
            smem + lrow * 512 + (cbyte ^ ((lrow & 7) << 4)) + (fr & 7) * 2) = f2bf(v);
      }
    }
  }
  asm volatile("s_waitcnt lgkmcnt(0)\ns_barrier" ::: "memory");  // writes visible

  // small GEMM: 16 row-groups of 16; contract 256 h-cols (8 x K32) with Vt
  const unsigned short* const VtE = Vt + (size_t)e * 16 * kH + (size_t)fr * kH + bcol;
  bf16x8 gv[8];
#pragma unroll
  for (int kk = 0; kk < 8; ++kk)
    gv[kk] = *reinterpret_cast<const bf16x8*>(VtE + kk * 32 + jg * 8);
#pragma unroll
  for (int f = 0; f < 2; ++f) {
    const int rowl = (2 * w + f) * 16 + fr;
    f32x4 pc = (f32x4){0.f, 0.f, 0.f, 0.f};
#pragma unroll
    for (int kk = 0; kk < 8; ++kk) {
      bf16x8 ga = *reinterpret_cast<const bf16x8*>(
          smem + rowl * 512 + ((((kk * 4 + jg)) ^ (rowl & 7)) << 4));
      pc = __builtin_amdgcn_mfma_f32_16x16x32_bf16(ga, gv[kk], pc, 0, 0, 0);
    }
    const int rowg = brow + (2 * w + f) * 16 + jg * 4;
#pragma unroll
    for (int j = 0; j < 4; ++j) {
      const float val = pc[j] * rr[(size_t)(rowg + j) * kE + e];
      atomicAdd(&part[(size_t)(rowg + j) * 16 + fr], val);
    }
  }
#undef MFMA16
#undef BARP
}

// ------- combine: y[b][c] = part[b][c] + sum_e r[b][e]*u[e][c] + bc[c] -------
__global__ __launch_bounds__(256) void k_combine(const float* __restrict__ part,
                                                 const float* __restrict__ rr,
                                                 const float* __restrict__ u,
                                                 const float* __restrict__ bc,
                                                 float* __restrict__ y) {
  const int tid = threadIdx.x;
  const int rloc = tid >> 4, c = tid & 15;
  const int b = blockIdx.x * 16 + rloc;
  if (c >= kC) return;
  float acc = part[(size_t)b * 16 + c] + bc[c];
#pragma unroll
  for (int e = 0; e < kE; ++e) acc += rr[(size_t)b * kE + e] * u[e * 16 + c];
  y[(size_t)b * kC + c] = acc;
}

extern "C" void kernel_launch(void* const* d_in, const int* in_sizes, int n_in,
                              void* d_out, int out_size, void* d_ws, size_t ws_size,
                              hipStream_t stream) {
  (void)in_sizes; (void)n_in; (void)out_size; (void)ws_size;
  const float* x  = (const float*)d_in[0];
  const float* Wr = (const float*)d_in[1];
  const float* br = (const float*)d_in[2];
  const float* W1 = (const float*)d_in[3];
  const float* b1 = (const float*)d_in[4];
  const float* W2 = (const float*)d_in[5];
  const float* b2 = (const float*)d_in[6];
  const float* Wc = (const float*)d_in[7];
  const float* bc = (const float*)d_in[8];
  float* y = (float*)d_out;

  // workspace carve (~82 MB)
  char* p = (char*)d_ws;
  unsigned short* xb  = (unsigned short*)p; p += (size_t)kB * kD * 2;        // 16 MB
  unsigned short* W1t = (unsigned short*)p; p += (size_t)kE * kH * kD * 2;   // 64 MB
  unsigned short* Vt  = (unsigned short*)p; p += (size_t)kE * 16 * kH * 2;   // 1 MB
  float* r    = (float*)p;                  p += (size_t)kB * kE * 4;        // 256 KB
  float* u    = (float*)p;                  p += (size_t)kE * 16 * 4;        // 512 B
  float* part = (float*)p;                  p += (size_t)kB * 16 * 4;        // 512 KB

  k_prep_all<<<dim3(39937), dim3(256), 0, stream>>>(
      x, Wr, br, W1, W2, Wc, b2, xb, W1t, Vt, r, part, u);

  k_moe_fused256<<<dim3(kB / 256, kH / 256, kE), dim3(512), 0, stream>>>(
      xb, W1t, b1, Vt, r, part);

  k_combine<<<dim3(kB / 16), dim3(256), 0, stream>>>(part, r, u, bc, y);
}

// Round 15
// 686.435 us; speedup vs baseline: 1.2748x; 1.2748x over previous
//
#include <hip/hip_runtime.h>
#include <cstdint>
#include <cstddef>

using bf16x8 = __attribute__((ext_vector_type(8))) short;
using f32x4  = __attribute__((ext_vector_type(4))) float;

constexpr int kB = 8192;
constexpr int kD = 1024;
constexpr int kE = 8;
constexpr int kH = 4096;
constexpr int kC = 10;

__device__ __forceinline__ unsigned short f2bf(float f) {
  unsigned int u = __float_as_uint(f);
  u += 0x7FFFu + ((u >> 16) & 1u);   // round-to-nearest-even (finite inputs)
  return (unsigned short)(u >> 16);
}

#define GLD16(gptr, lptr)                                                      \
  __builtin_amdgcn_global_load_lds(                                            \
      (const __attribute__((address_space(1))) void*)(gptr),                   \
      (__attribute__((address_space(3))) void*)(lptr), 16, 0, 0)

// ============================================================================
// k_prep: fused {x f32->bf16 convert | routing softmax | part zero | u build}
// (proven r6/r9/r10/r13).  flat grid partition; disjoint outputs.
// ============================================================================
__global__ __launch_bounds__(256) void k_prep(const float* __restrict__ x,
                                              const float* __restrict__ Wr,
                                              const float* __restrict__ br,
                                              const float* __restrict__ b2,
                                              const float* __restrict__ Wc,
                                              unsigned short* __restrict__ xb,
                                              float* __restrict__ r,
                                              float* __restrict__ part,
                                              float* __restrict__ u) {
  const int bid = blockIdx.x;
  const int t = threadIdx.x;
  if (bid < 4096) {  // ---- convert x ----
    const long i = ((long)bid * 256 + t) * 8;
    float4 a = *reinterpret_cast<const float4*>(x + i);
    float4 b = *reinterpret_cast<const float4*>(x + i + 4);
    bf16x8 o;
    o[0] = (short)f2bf(a.x); o[1] = (short)f2bf(a.y);
    o[2] = (short)f2bf(a.z); o[3] = (short)f2bf(a.w);
    o[4] = (short)f2bf(b.x); o[5] = (short)f2bf(b.y);
    o[6] = (short)f2bf(b.z); o[7] = (short)f2bf(b.w);
    *reinterpret_cast<bf16x8*>(xb + i) = o;
  } else if (bid < 6144) {  // ---- routing softmax ----
    const int w = t >> 6, l = t & 63;
    const int b = (bid - 4096) * 4 + w;
    const float* xr = x + (size_t)b * kD;
    float acc[kE];
#pragma unroll
    for (int e = 0; e < kE; ++e) acc[e] = 0.f;
    for (int d = l; d < kD; d += 64) {
      const float xv = xr[d];
      const float* wrow = Wr + d * kE;
#pragma unroll
      for (int e = 0; e < kE; ++e) acc[e] += xv * wrow[e];
    }
#pragma unroll
    for (int e = 0; e < kE; ++e) {
#pragma unroll
      for (int s = 32; s > 0; s >>= 1) acc[e] += __shfl_xor(acc[e], s);
      acc[e] += br[e];
    }
    float mx = acc[0];
#pragma unroll
    for (int e = 1; e < kE; ++e) mx = fmaxf(mx, acc[e]);
    float sum = 0.f;
#pragma unroll
    for (int e = 0; e < kE; ++e) { acc[e] = expf(acc[e] - mx); sum += acc[e]; }
    const float inv = 1.f / sum;
    float val = 0.f;
#pragma unroll
    for (int e = 0; e < kE; ++e) if (l == e) val = acc[e] * inv;
    if (l < kE) r[(size_t)b * kE + l] = val;
  } else if (bid < 6656) {  // ---- zero part ----
    part[(size_t)(bid - 6144) * 256 + t] = 0.f;
  } else {  // ---- ubuild ----
    if (t >= kE * kC) return;
    const int e = t / kC, c = t % kC;
    float acc = 0.f;
    for (int d = 0; d < kD; ++d) acc += b2[e * kD + d] * Wc[d * kC + c];
    u[e * 16 + c] = acc;
  }
}

// ------------- transpose+convert W1 [E][D][H] f32 -> W1t [E][H][D] bf16 -------------
__global__ __launch_bounds__(256) void k_transpose_w(const float* __restrict__ W,
                                                     unsigned short* __restrict__ Wt,
                                                     int K, int N) {
  __shared__ unsigned short tile[32][33];
  const int e = blockIdx.z;
  const int n0 = blockIdx.x * 32, k0 = blockIdx.y * 32;
  const int tx = threadIdx.x, ty = threadIdx.y;  // (32,8)
  const float* Wb = W + (size_t)e * K * N;
  unsigned short* Wtb = Wt + (size_t)e * N * K;
#pragma unroll
  for (int j = 0; j < 32; j += 8)
    tile[ty + j][tx] = f2bf(Wb[(size_t)(k0 + ty + j) * N + n0 + tx]);
  __syncthreads();
#pragma unroll
  for (int j = 0; j < 32; j += 8)
    Wtb[(size_t)(n0 + ty + j) * K + k0 + tx] = tile[tx][ty + j];
}

// ------- V-build: Vt[e][c][h] = sum_d W2[e][h][d]*Wc[d][c]; rows c>=10 zeroed -------
// 4 lanes per row (d-quartered), WcL staged in LDS (proven r13 config).
__global__ __launch_bounds__(256) void k_vbuild(const float* __restrict__ W2,
                                                const float* __restrict__ Wc,
                                                unsigned short* __restrict__ Vt) {
  __shared__ float WcL[kD * kC];  // 40 KB
  for (int i = threadIdx.x; i < kD * kC; i += 256) WcL[i] = Wc[i];
  __syncthreads();
  const int gid = blockIdx.x * 256 + threadIdx.x;  // 0..131071
  const int row = gid >> 2;        // e*4096 + h
  const int q   = gid & 3;         // d-quarter
  const int e = row >> 12, hrow = row & 4095;
  const float4* w2q = reinterpret_cast<const float4*>(W2 + (size_t)row * kD + q * 256);
  float acc[kC];
#pragma unroll
  for (int c = 0; c < kC; ++c) acc[c] = 0.f;
#pragma unroll 4
  for (int i = 0; i < 64; ++i) {
    float4 w = w2q[i];
    const float* wc0 = WcL + (q * 256 + i * 4) * kC;
#pragma unroll
    for (int c = 0; c < kC; ++c)
      acc[c] += w.x * wc0[c] + w.y * wc0[kC + c] + w.z * wc0[2 * kC + c] +
                w.w * wc0[3 * kC + c];
  }
#pragma unroll
  for (int c = 0; c < kC; ++c) {
    acc[c] += __shfl_xor(acc[c], 1);
    acc[c] += __shfl_xor(acc[c], 2);
  }
  if (q == 0) {
    unsigned short* vte = Vt + (size_t)e * 16 * kH;
#pragma unroll
    for (int c = 0; c < kC; ++c) vte[(size_t)c * kH + hrow] = f2bf(acc[c]);
#pragma unroll
    for (int c = kC; c < 16; ++c) vte[(size_t)c * kH + hrow] = 0;
  }
}

// ============================================================================
// fused 256x256 8-phase GEMM1 + V-contraction  (r14 fused verbatim — best:
// 578-589 µs, MfmaUtil 43.2-43.6%, VGPR 120)
//   part[b][c] += r[b,e] * sum_h relu(x@W1[e]+b1[e])[b,h] * Vt[e][c][h]
// ph1 stages BOTH Y.A halves -> extra DMA flight before ph4 gate.  Ledger:
// ph4 outstanding = Y.B(4)+Y.A(4)+X'.B(4)=12, vmcnt(4) drains KT(2i+1);
// ph8 = X'.B+X'.A+Y'.B=12, vmcnt(4) drains KT(2i+2).
// HARD WALLS (measured r5/r7/r8/r11/r12): no reg-prefetch (VGPR spill), no
// >128KB LDS, no B-from-global (latency), no in-block e-loop (L2 locality).
// ============================================================================
__global__ __launch_bounds__(512, 2) void k_moe_fused256(
    const unsigned short* __restrict__ xb,   // [B][D] bf16
    const unsigned short* __restrict__ W1t,  // [E][H][D] bf16
    const float* __restrict__ b1,            // [E][H]
    const unsigned short* __restrict__ Vt,   // [E][16][H] bf16
    const float* __restrict__ rr,            // [B][E]
    float* __restrict__ part) {              // [B][16] f32 (atomic accum)
  __shared__ __align__(16) char smem[131072];
  constexpr int K = kD;          // 1024
  constexpr int NIT = K / 128;   // 8 iterations, 2 K-tiles (BK=64) each

  const int e = blockIdx.z;
  const int bx = (blockIdx.x & 7) * 4 + (blockIdx.x >> 3);  // bijective XCD swizzle (32%8==0)
  const int brow = bx * 256, bcol = blockIdx.y * 256;
  const unsigned short* const At = xb;
  const unsigned short* const Bt = W1t + (size_t)e * kH * kD;

  const int tid = threadIdx.x;
  const int w = tid >> 6, l = tid & 63;
  const int wr = w >> 2, wc = w & 3;       // wave grid 2M x 4N
  const int fr = l & 15, jg = l >> 4;      // fragment row / k-chunk group

  // fragment-read swizzled chunk offsets (row&7 == fr&7 since all row bases %16==0)
  int ck[2];
#pragma unroll
  for (int k = 0; k < 2; ++k) ck[k] = (((k * 4 + jg) ^ (fr & 7)) << 4);
  const int abase = wr * 16384;                 // + buf*65536           (A region)
  const int bbase = 32768 + (wc >> 1) * 16384;  // + buf*65536           (B region)
  const int brow0 = (wc & 1) * 64;              // B row base within half

  // staging: linear LDS dest, inverse-swizzled global source (rule 21)
  const int p0 = w * 64 + l;            // phys 16B chunk within an 8KB round
  const int rp = p0 >> 3;               // row 0..63 (round 0); +64 for round 1
  const int cs = (p0 & 7) ^ (rp & 7);   // logical chunk (same both rounds)
  const size_t aofs = (size_t)(brow + rp) * K + cs * 8;
  const size_t bofs = (size_t)(bcol + rp) * K + cs * 8;
  const int ldst = w * 1024;            // wave-uniform LDS dest offset

#define STG_A(buf, ht, kt)                                                     \
  do {                                                                         \
    GLD16(At + aofs + (size_t)(ht) * 131072 + (size_t)(kt) * 64,               \
          smem + (buf) * 65536 + (ht) * 16384 + ldst);                         \
    GLD16(At + aofs + (size_t)(ht) * 131072 + 65536 + (size_t)(kt) * 64,       \
          smem + (buf) * 65536 + (ht) * 16384 + 8192 + ldst);                  \
  } while (0)
#define STG_B(buf, ht, kt)                                                     \
  do {                                                                         \
    GLD16(Bt + bofs + (size_t)(ht) * 131072 + (size_t)(kt) * 64,               \
          smem + (buf) * 65536 + 32768 + (ht) * 16384 + ldst);                 \
    GLD16(Bt + bofs + (size_t)(ht) * 131072 + 65536 + (size_t)(kt) * 64,       \
          smem + (buf) * 65536 + 32768 + (ht) * 16384 + 8192 + ldst);          \
  } while (0)

#define READ_A(buf, mp)                                                        \
  do {                                                                         \
    _Pragma("unroll") for (int mm = 0; mm < 2; ++mm)                           \
    _Pragma("unroll") for (int k = 0; k < 2; ++k)                              \
      aq[mm][k] = *reinterpret_cast<const bf16x8*>(                            \
          smem + (buf) * 65536 + abase + (((mp) * 2 + mm) * 16 + fr) * 128 + ck[k]); \
  } while (0)
#define READ_B(buf)                                                            \
  do {                                                                         \
    _Pragma("unroll") for (int n = 0; n < 4; ++n)                              \
    _Pragma("unroll") for (int k = 0; k < 2; ++k)                              \
      bq[n][k] = *reinterpret_cast<const bf16x8*>(                             \
          smem + (buf) * 65536 + bbase + (brow0 + n * 16 + fr) * 128 + ck[k]); \
  } while (0)
#define MFMA16(mp)                                                             \
  do {                                                                         \
    __builtin_amdgcn_s_setprio(1);                                             \
    _Pragma("unroll") for (int mm = 0; mm < 2; ++mm)                           \
    _Pragma("unroll") for (int n = 0; n < 4; ++n)                              \
    _Pragma("unroll") for (int k = 0; k < 2; ++k)                              \
      acc[(mp) * 2 + mm][n] = __builtin_amdgcn_mfma_f32_16x16x32_bf16(         \
          aq[mm][k], bq[n][k], acc[(mp) * 2 + mm][n], 0, 0, 0);                \
    __builtin_amdgcn_s_setprio(0);                                             \
  } while (0)
#define BARP() asm volatile("s_barrier" ::: "memory")

  bf16x8 aq[2][2], bq[4][2];
  f32x4 acc[8][4];
#pragma unroll
  for (int m = 0; m < 8; ++m)
#pragma unroll
    for (int n = 0; n < 4; ++n) acc[m][n] = (f32x4){0.f, 0.f, 0.f, 0.f};

  // prologue: X=buf0 gets KT0 (full), Y=buf1 gets KT1's B halves; Y.A comes in ph1
  STG_A(0, 0, 0); STG_A(0, 1, 0); STG_B(0, 0, 0); STG_B(0, 1, 0);
  STG_B(1, 0, 1); STG_B(1, 1, 1);
  asm volatile("s_waitcnt vmcnt(4)" ::: "memory");  // KT0 landed; Y.B (4) in flight
  BARP();

  for (int i = 0; i < NIT; ++i) {
    const bool g = (i < NIT - 1);
    const int kx = 2 * i + 2, ky = 2 * i + 3;
    // ---- ph1: X m-pair0; stage BOTH Y.A halves [Y.A free since prev ph8] ----
    READ_A(0, 0); READ_B(0);
    STG_A(1, 0, 2 * i + 1); STG_A(1, 1, 2 * i + 1);
    BARP(); MFMA16(0); BARP();
    // ---- ph2: X m-pair1; stage X'.B0 [X.B free after ph1] ----
    READ_A(0, 1);
    if (g) STG_B(0, 0, kx);
    BARP(); MFMA16(1); BARP();
    // ---- ph3: X m-pair2; stage X'.B1 ----
    READ_A(0, 2);
    if (g) STG_B(0, 1, kx);
    BARP(); MFMA16(2); BARP();
    // ---- ph4: X m-pair3; vmcnt forces Y=KT(2i+1) complete ----
    READ_A(0, 3);
    BARP(); MFMA16(3);
    if (g) asm volatile("s_waitcnt vmcnt(4)" ::: "memory");
    else   asm volatile("s_waitcnt vmcnt(0)" ::: "memory");
    BARP();
    // ---- ph5: Y m-pair0; stage X'.A0+A1 [X.A free after ph4] ----
    READ_A(1, 0); READ_B(1);
    if (g) { STG_A(0, 0, kx); STG_A(0, 1, kx); }
    BARP(); MFMA16(0); BARP();
    // ---- ph6: Y m-pair1; stage Y'.B0 [Y.B free after ph5] ----
    READ_A(1, 1);
    if (g) STG_B(1, 0, ky);
    BARP(); MFMA16(1); BARP();
    // ---- ph7: Y m-pair2; stage Y'.B1 ----
    READ_A(1, 2);
    if (g) STG_B(1, 1, ky);
    BARP(); MFMA16(2); BARP();
    // ---- ph8: Y m-pair3; vmcnt forces X'=KT(2i+2) complete ----
    READ_A(1, 3);
    BARP(); MFMA16(3);
    if (g) asm volatile("s_waitcnt vmcnt(4)" ::: "memory");
    BARP();
  }
#undef STG_A
#undef STG_B
#undef READ_A
#undef READ_B

  // ===== epilogue: g = relu(acc+b1) -> LDS [256][256] bf16 (swizzled), then g x V^T =====
#pragma unroll
  for (int n = 0; n < 4; ++n) {
    const int lcol = wc * 64 + n * 16 + fr;
    const float bias = b1[(size_t)e * kH + bcol + lcol];
    const int cbyte = (lcol >> 3) << 4;
#pragma unroll
    for (int m = 0; m < 8; ++m) {
#pragma unroll
      for (int j = 0; j < 4; ++j) {
        const int lrow = wr * 128 + m * 16 + jg * 4 + j;
        const float v = fmaxf(acc[m][n][j] + bias, 0.f);
        *reinterpret_cast<unsigned short*>(
            smem + lrow * 512 + (cbyte ^ ((lrow & 7) << 4)) + (fr & 7) * 2) = f2bf(v);
      }
    }
  }
  asm volatile("s_waitcnt lgkmcnt(0)\ns_barrier" ::: "memory");  // writes visible

  // small GEMM: 16 row-groups of 16; contract 256 h-cols (8 x K32) with Vt
  const unsigned short* const VtE = Vt + (size_t)e * 16 * kH + (size_t)fr * kH + bcol;
  bf16x8 gv[8];
#pragma unroll
  for (int kk = 0; kk < 8; ++kk)
    gv[kk] = *reinterpret_cast<const bf16x8*>(VtE + kk * 32 + jg * 8);
#pragma unroll
  for (int f = 0; f < 2; ++f) {
    const int rowl = (2 * w + f) * 16 + fr;
    f32x4 pc = (f32x4){0.f, 0.f, 0.f, 0.f};
#pragma unroll
    for (int kk = 0; kk < 8; ++kk) {
      bf16x8 ga = *reinterpret_cast<const bf16x8*>(
          smem + rowl * 512 + ((((kk * 4 + jg)) ^ (rowl & 7)) << 4));
      pc = __builtin_amdgcn_mfma_f32_16x16x32_bf16(ga, gv[kk], pc, 0, 0, 0);
    }
    const int rowg = brow + (2 * w + f) * 16 + jg * 4;
#pragma unroll
    for (int j = 0; j < 4; ++j) {
      const float val = pc[j] * rr[(size_t)(rowg + j) * kE + e];
      atomicAdd(&part[(size_t)(rowg + j) * 16 + fr], val);
    }
  }
#undef MFMA16
#undef BARP
}

// ------- combine: y[b][c] = part[b][c] + sum_e r[b][e]*u[e][c] + bc[c] -------
__global__ __launch_bounds__(256) void k_combine(const float* __restrict__ part,
                                                 const float* __restrict__ rr,
                                                 const float* __restrict__ u,
                                                 const float* __restrict__ bc,
                                                 float* __restrict__ y) {
  const int tid = threadIdx.x;
  const int rloc = tid >> 4, c = tid & 15;
  const int b = blockIdx.x * 16 + rloc;
  if (c >= kC) return;
  float acc = part[(size_t)b * 16 + c] + bc[c];
#pragma unroll
  for (int e = 0; e < kE; ++e) acc += rr[(size_t)b * kE + e] * u[e * 16 + c];
  y[(size_t)b * kC + c] = acc;
}

extern "C" void kernel_launch(void* const* d_in, const int* in_sizes, int n_in,
                              void* d_out, int out_size, void* d_ws, size_t ws_size,
                              hipStream_t stream) {
  (void)in_sizes; (void)n_in; (void)out_size; (void)ws_size;
  const float* x  = (const float*)d_in[0];
  const float* Wr = (const float*)d_in[1];
  const float* br = (const float*)d_in[2];
  const float* W1 = (const float*)d_in[3];
  const float* b1 = (const float*)d_in[4];
  const float* W2 = (const float*)d_in[5];
  const float* b2 = (const float*)d_in[6];
  const float* Wc = (const float*)d_in[7];
  const float* bc = (const float*)d_in[8];
  float* y = (float*)d_out;

  // workspace carve (~82 MB)
  char* p = (char*)d_ws;
  unsigned short* xb  = (unsigned short*)p; p += (size_t)kB * kD * 2;        // 16 MB
  unsigned short* W1t = (unsigned short*)p; p += (size_t)kE * kH * kD * 2;   // 64 MB
  unsigned short* Vt  = (unsigned short*)p; p += (size_t)kE * 16 * kH * 2;   // 1 MB
  float* r    = (float*)p;                  p += (size_t)kB * kE * 4;        // 256 KB
  float* u    = (float*)p;                  p += (size_t)kE * 16 * 4;        // 512 B
  float* part = (float*)p;                  p += (size_t)kB * 16 * 4;        // 512 KB

  k_prep<<<dim3(6657), dim3(256), 0, stream>>>(x, Wr, br, b2, Wc, xb, r, part, u);
  k_transpose_w<<<dim3(kH / 32, kD / 32, kE), dim3(32, 8), 0, stream>>>(W1, W1t, kD, kH);
  k_vbuild<<<dim3(kE * kH * 4 / 256), dim3(256), 0, stream>>>(W2, Wc, Vt);

  k_moe_fused256<<<dim3(kB / 256, kH / 256, kE), dim3(512), 0, stream>>>(
      xb, W1t, b1, Vt, r, part);

  k_combine<<<dim3(kB / 16), dim3(256), 0, stream>>>(part, r, u, bc, y);
}